// Round 1
// baseline (909.038 us; speedup 1.0000x reference)
//
#include <hip/hip_runtime.h>
#include <math.h>

#define FFT_N   2046
#define IN_N    1024
#define NROWS   8192      // rows per tensor (32*64*4)
#define NK      1024      // unique spectrum bins 0..1023 (symmetry)

// ---------------------------------------------------------------------------
// Kernel 1: twiddle table.  W rows 0..1023 = cos(2*pi*k*n/2046),
// rows 1024..2047 = sin(2*pi*k*n/2046).  Angle via integer (k*n) mod 2046
// so sinf/cosf see small args (no large-arg reduction error).
// ---------------------------------------------------------------------------
__global__ void twiddle_kernel(float* __restrict__ W) {
    int row = blockIdx.x;            // 0..2047
    int k = row & 1023;
    bool is_sin = row >= 1024;
    int n4 = threadIdx.x * 4;        // 256 threads * 4 = 1024 cols
    const float c = 6.28318530717958647692f / 2046.0f;
    float4 v;
    #pragma unroll
    for (int i = 0; i < 4; ++i) {
        int n = n4 + i;
        int m = (k * n) % FFT_N;     // k*n < 2^21, fits easily
        float a = (float)m * c;
        ((float*)&v)[i] = is_sin ? sinf(a) : cosf(a);
    }
    *(float4*)(W + (size_t)row * IN_N + n4) = v;
}

// ---------------------------------------------------------------------------
// Kernel 2: fused cos/sin GEMM + |.|^2.
//   Re[k,r] = sum_n Wc[k,n]*X[r,n];  Im[k,r] = sum_n Ws[k,n]*X[r,n]
//   pdp[r,k] = (Re^2 + Im^2) / 2046^2
// M=1024 (k) x N=16384 (r, pred rows then tgt rows) x K=1024 (n).
// 64x64 tile, BK=32, 256 threads, 4x4 microtile per thread (x2 for Re/Im).
// ---------------------------------------------------------------------------
#define BM 64
#define BN 64
#define BK 32

__global__ __launch_bounds__(256) void dft_pdp_kernel(
    const float* __restrict__ pred, const float* __restrict__ tgt,
    const float* __restrict__ W, float* __restrict__ pdp) {

    // transposed tiles [kk][m], row stride 68 floats = 272B (16B aligned)
    __shared__ __align__(16) float Ac[BK][BM + 4];
    __shared__ __align__(16) float As[BK][BM + 4];
    __shared__ __align__(16) float Xb[BK][BN + 4];

    const int k0 = blockIdx.x * BM;       // 0..960
    const int r0 = blockIdx.y * BN;       // 0..16320
    const float* X = (r0 < NROWS) ? (pred + (size_t)r0 * IN_N)
                                  : (tgt  + (size_t)(r0 - NROWS) * IN_N);
    const float* Wc = W + (size_t)k0 * IN_N;
    const float* Ws = W + (size_t)(1024 + k0) * IN_N;

    const int t  = threadIdx.x;
    const int tc = t & 15;                // k-frag group (16)
    const int tr = t >> 4;                // r-frag group (16)

    float accRe[4][4] = {{0.f}}, accIm[4][4] = {{0.f}};

    for (int kb = 0; kb < IN_N; kb += BK) {
        #pragma unroll
        for (int l = 0; l < 2; ++l) {
            int f   = t + 256 * l;        // 0..511 float4 units (64 rows x 8)
            int row = f >> 3;
            int cc  = f & 7;
            size_t go = (size_t)row * IN_N + kb + cc * 4;
            float4 a = *(const float4*)(Wc + go);
            float4 s = *(const float4*)(Ws + go);
            float4 x = *(const float4*)(X  + go);
            #pragma unroll
            for (int i = 0; i < 4; ++i) {
                Ac[cc * 4 + i][row] = ((float*)&a)[i];
                As[cc * 4 + i][row] = ((float*)&s)[i];
                Xb[cc * 4 + i][row] = ((float*)&x)[i];
            }
        }
        __syncthreads();
        #pragma unroll
        for (int kk = 0; kk < BK; ++kk) {
            float4 af = *(const float4*)&Ac[kk][tc * 4];
            float4 sf = *(const float4*)&As[kk][tc * 4];
            float4 xf = *(const float4*)&Xb[kk][tr * 4];
            #pragma unroll
            for (int i = 0; i < 4; ++i) {
                #pragma unroll
                for (int j = 0; j < 4; ++j) {
                    accRe[i][j] = fmaf(((float*)&af)[i], ((float*)&xf)[j], accRe[i][j]);
                    accIm[i][j] = fmaf(((float*)&sf)[i], ((float*)&xf)[j], accIm[i][j]);
                }
            }
        }
        __syncthreads();
    }

    const float invN2 = 1.0f / ((float)FFT_N * (float)FFT_N);
    #pragma unroll
    for (int j = 0; j < 4; ++j) {
        float4 o;
        #pragma unroll
        for (int i = 0; i < 4; ++i) {
            float re = accRe[i][j], im = accIm[i][j];
            ((float*)&o)[i] = (re * re + im * im) * invN2;
        }
        *(float4*)(pdp + (size_t)(r0 + tr * 4 + j) * NK + k0 + tc * 4) = o;
    }
}

// ---------------------------------------------------------------------------
// Kernel 3: per-row stats.  One block per row-pair (pred r, tgt r).
// Uses spectrum symmetry: weight 2 for k=1..1022, weight 1 for k=0,1023.
//   energy, max, min  -> normalize, rng, softmax coef
//   delay = 1023*(1 - w0)  =>  |d_p - d_t|/2046 = 0.5*|w0_p - w0_t|
// ---------------------------------------------------------------------------
__device__ __forceinline__ float breduce(float v, float* red, int t, int op) {
    __syncthreads();                 // protect previous use of red
    red[t] = v;
    __syncthreads();
    for (int s = 128; s > 0; s >>= 1) {
        if (t < s) {
            float a = red[t], b = red[t + s];
            red[t] = (op == 0) ? (a + b) : (op == 1) ? fmaxf(a, b) : fminf(a, b);
        }
        __syncthreads();
    }
    return red[0];
}

__global__ __launch_bounds__(256) void row_stats_kernel(
    const float* __restrict__ pdp,
    float* __restrict__ mse_rows, float* __restrict__ dd_rows) {

    __shared__ float red[256];
    const int r = blockIdx.x;
    const int t = threadIdx.x;
    const float* pp = pdp + (size_t)r * NK;
    const float* pt = pdp + (size_t)(NROWS + r) * NK;
    float4 vp = *(const float4*)(pp + t * 4);
    float4 vt = *(const float4*)(pt + t * 4);

    float wsp = 0.f, wst = 0.f;
    float mxp = -1e30f, mnp = 1e30f, mxt = -1e30f, mnt = 1e30f;
    #pragma unroll
    for (int i = 0; i < 4; ++i) {
        int k = t * 4 + i;
        float w = (k == 0 || k == 1023) ? 1.f : 2.f;
        float a = ((float*)&vp)[i], b = ((float*)&vt)[i];
        wsp += w * a;            wst += w * b;
        mxp = fmaxf(mxp, a);     mnp = fminf(mnp, a);
        mxt = fmaxf(mxt, b);     mnt = fminf(mnt, b);
    }
    float Ep  = breduce(wsp, red, t, 0);
    float Et  = breduce(wst, red, t, 0);
    float Mp  = breduce(mxp, red, t, 1);
    float mp_ = breduce(mnp, red, t, 2);
    float Mt  = breduce(mxt, red, t, 1);
    float mt_ = breduce(mnt, red, t, 2);

    float scp = (Ep < 1e-8f) ? 1.f : 1.f / Ep;
    float sct = (Et < 1e-8f) ? 1.f : 1.f / Et;
    float rngp = fmaxf(scp * (Mp - mp_), 1e-8f);
    float rngt = fmaxf(sct * (Mt - mt_), 1e-8f);
    float cfp = 10.f * scp / rngp;        // s_k = cfp * raw_pdp_k
    float cft = 10.f * sct / rngt;
    float smp = cfp * Mp;                 // max of s (cfp > 0)
    float smt = cft * Mt;

    float zp = 0.f, zt = 0.f, ms = 0.f;
    #pragma unroll
    for (int i = 0; i < 4; ++i) {
        int k = t * 4 + i;
        float w = (k == 0 || k == 1023) ? 1.f : 2.f;
        float a = ((float*)&vp)[i], b = ((float*)&vt)[i];
        zp += w * __expf(0.f) * 0.f + w * expf(cfp * a - smp);   // plain expf
        zt += w * expf(cft * b - smt);
        float d = a * scp - b * sct;
        ms += w * d * d;
    }
    float Zp  = breduce(zp, red, t, 0);
    float Zt  = breduce(zt, red, t, 0);
    float MSE = breduce(ms, red, t, 0);

    if (t == 0) {
        float w0p = expf(cfp * ((float*)&vp)[0] - smp) / Zp;   // k=0 lives in thread 0
        float w0t = expf(cft * ((float*)&vt)[0] - smt) / Zt;
        mse_rows[r] = MSE;
        dd_rows[r]  = 0.5f * fabsf(w0p - w0t);
    }
}

// ---------------------------------------------------------------------------
// Kernel 4: final scalar reduce over 8192 rows.
// ---------------------------------------------------------------------------
__global__ __launch_bounds__(256) void final_kernel(
    const float* __restrict__ mse_rows, const float* __restrict__ dd_rows,
    float* __restrict__ out) {
    __shared__ float r1[256];
    __shared__ float r2[256];
    int t = threadIdx.x;
    float s1 = 0.f, s2 = 0.f;
    for (int r = t; r < NROWS; r += 256) { s1 += mse_rows[r]; s2 += dd_rows[r]; }
    r1[t] = s1; r2[t] = s2;
    __syncthreads();
    for (int s = 128; s > 0; s >>= 1) {
        if (t < s) { r1[t] += r1[t + s]; r2[t] += r2[t + s]; }
        __syncthreads();
    }
    if (t == 0) {
        float mse = r1[0] / ((float)NROWS * (float)FFT_N);
        float dl  = r2[0] / (float)NROWS;
        out[0] = 0.7f * mse + 0.3f * dl;
    }
}

// ---------------------------------------------------------------------------
extern "C" void kernel_launch(void* const* d_in, const int* in_sizes, int n_in,
                              void* d_out, int out_size, void* d_ws, size_t ws_size,
                              hipStream_t stream) {
    const float* pred = (const float*)d_in[0];
    const float* tgt  = (const float*)d_in[1];
    float* out = (float*)d_out;

    char* ws = (char*)d_ws;
    float* W        = (float*)ws;                                   // 8 MiB
    float* pdp      = (float*)(ws + (size_t)8  * 1024 * 1024);      // 64 MiB
    float* mse_rows = (float*)(ws + (size_t)72 * 1024 * 1024);      // 32 KiB
    float* dd_rows  = mse_rows + NROWS;                             // 32 KiB

    twiddle_kernel<<<2048, 256, 0, stream>>>(W);

    dim3 g2(IN_N / BM, (2 * NROWS) / BN);   // (16, 256)
    dft_pdp_kernel<<<g2, 256, 0, stream>>>(pred, tgt, W, pdp);

    row_stats_kernel<<<NROWS, 256, 0, stream>>>(pdp, mse_rows, dd_rows);

    final_kernel<<<1, 256, 0, stream>>>(mse_rows, dd_rows, out);
}

// Round 2
// 352.754 us; speedup vs baseline: 2.5770x; 2.5770x over previous
//
#include <hip/hip_runtime.h>
#include <math.h>

#define IN_N   1024
#define NROWS  8192      // rows per tensor
#define NTOT   16384     // both tensors
#define FFT_N  2046

typedef unsigned short u16;
typedef __attribute__((ext_vector_type(8))) __bf16 bf16x8;
typedef __attribute__((ext_vector_type(4))) float  f32x4;

// ---- bf16 helpers (RTNE) --------------------------------------------------
__device__ __forceinline__ u16 f2bf(float f) {
    unsigned u = __builtin_bit_cast(unsigned, f);
    unsigned r = (u + 0x7fffu + ((u >> 16) & 1u)) >> 16;
    return (u16)r;
}
__device__ __forceinline__ float bf2f(u16 h) {
    unsigned u = ((unsigned)h) << 16;
    return __builtin_bit_cast(float, u);
}

// ---- async global->LDS, 16B per lane --------------------------------------
__device__ __forceinline__ void gload_lds16(const void* g, void* l) {
    __builtin_amdgcn_global_load_lds(
        (__attribute__((address_space(1))) void*)g,
        (__attribute__((address_space(3))) void*)l, 16, 0, 0);
}

// ---------------------------------------------------------------------------
// Kernel 1: twiddle tables, split into bf16 hi+lo.
// Wc = cos(2*pi*k*n/2046), Ws = sin(...), k,n in [0,1024).
// ---------------------------------------------------------------------------
__global__ void twiddle_kernel(u16* __restrict__ Wch, u16* __restrict__ Wcl,
                               u16* __restrict__ Wsh, u16* __restrict__ Wsl) {
    int k = blockIdx.x;
    int n0 = threadIdx.x * 4;
    const float c = 6.28318530717958647692f / 2046.0f;
    #pragma unroll
    for (int i = 0; i < 4; ++i) {
        int n = n0 + i;
        int m = (k * n) % FFT_N;
        float a = (float)m * c;
        float sv, cv;
        sincosf(a, &sv, &cv);
        u16 ch = f2bf(cv); u16 cl = f2bf(cv - bf2f(ch));
        u16 sh = f2bf(sv); u16 sl = f2bf(sv - bf2f(sh));
        size_t o = (size_t)k * IN_N + n;
        Wch[o] = ch; Wcl[o] = cl; Wsh[o] = sh; Wsl[o] = sl;
    }
}

// ---------------------------------------------------------------------------
// Kernel 2: convert X (pred ++ tgt) fp32 -> bf16 (RTNE).
// ---------------------------------------------------------------------------
__global__ __launch_bounds__(256) void convert_kernel(
    const float* __restrict__ pred, const float* __restrict__ tgt,
    u16* __restrict__ Xh) {
    size_t gid = (size_t)blockIdx.x * 256 + threadIdx.x;   // float4 index
    size_t e = gid * 4;
    const size_t half = (size_t)NROWS * IN_N;
    const float* s = (e < half) ? (pred + e) : (tgt + (e - half));
    float4 v = *(const float4*)s;
    ushort4 o;
    o.x = f2bf(v.x); o.y = f2bf(v.y); o.z = f2bf(v.z); o.w = f2bf(v.w);
    *(ushort4*)(Xh + e) = o;
}

// ---------------------------------------------------------------------------
// Kernel 3: MFMA DFT + |.|^2.
//   C_re[m][r] = sum_k W_cos[m][k] * X[r][k]   (B^T GEMM, K-concat hi/lo)
//   pdp[r][m]  = (Re^2 + Im^2) / 2046^2  (bf16)
// 128x128 tile, BK=32, 4 waves (2x2 of 64x64), dual accumulators Re/Im.
// ---------------------------------------------------------------------------
#define BM 128
#define BN 128
#define BK 32

__global__ __launch_bounds__(256) void dft_pdp_mfma(
    const u16* __restrict__ Wch, const u16* __restrict__ Wcl,
    const u16* __restrict__ Wsh, const u16* __restrict__ Wsl,
    const u16* __restrict__ Xh, u16* __restrict__ pdp) {

    __shared__ u16 Ac[BM][BK];   // cos tile (8 KB, linear for gload_lds)
    __shared__ u16 As[BM][BK];   // sin tile
    __shared__ u16 Bx[BN][BK];   // X tile

    const int m0 = blockIdx.x * BM;     // bin offset
    const int r0 = blockIdx.y * BN;     // X-row offset
    const int t    = threadIdx.x;
    const int w    = t >> 6;
    const int lane = t & 63;
    const int wm = (w & 1) * 64;        // wave's m offset in tile
    const int wr = (w >> 1) * 64;       // wave's r offset in tile

    const int lr = lane & 15;           // frag row
    const int lk = (lane >> 4) * 8;     // frag k offset

    f32x4 accRe[4][4], accIm[4][4];
    #pragma unroll
    for (int i = 0; i < 4; ++i)
        #pragma unroll
        for (int j = 0; j < 4; ++j)
            #pragma unroll
            for (int q = 0; q < 4; ++q) { accRe[i][j][q] = 0.f; accIm[i][j][q] = 0.f; }

    for (int kb = 0; kb < 2048; kb += BK) {
        const u16* wc = (kb < 1024) ? Wch : Wcl;
        const u16* ws = (kb < 1024) ? Wsh : Wsl;
        const int  kc = kb & 1023;

        // ---- stage 3 x 8KB tiles via global_load_lds (2 x 16B per thread each)
        #pragma unroll
        for (int it = 0; it < 2; ++it) {
            int off = it * 4096 + w * 1024 + lane * 16;  // byte offset in tile
            int row = off >> 6;                           // 64B per row
            int cb  = off & 63;
            size_t gofs = ((size_t)(m0 + row) * IN_N + kc) * 2 + cb;
            size_t xofs = ((size_t)(r0 + row) * IN_N + kc) * 2 + cb;
            char* lc = (char*)&Ac[0][0] + it * 4096 + w * 1024;  // wave-uniform
            char* ls = (char*)&As[0][0] + it * 4096 + w * 1024;
            char* lx = (char*)&Bx[0][0] + it * 4096 + w * 1024;
            gload_lds16((const char*)wc + gofs, lc);
            gload_lds16((const char*)ws + gofs, ls);
            gload_lds16((const char*)Xh + xofs, lx);
        }
        __syncthreads();

        // ---- fragments
        bf16x8 fa[4], fs[4], fb[4];
        #pragma unroll
        for (int i = 0; i < 4; ++i) {
            fa[i] = *(const bf16x8*)&Ac[wm + i * 16 + lr][lk];
            fs[i] = *(const bf16x8*)&As[wm + i * 16 + lr][lk];
        }
        #pragma unroll
        for (int j = 0; j < 4; ++j)
            fb[j] = *(const bf16x8*)&Bx[wr + j * 16 + lr][lk];

        // ---- 32 MFMAs
        #pragma unroll
        for (int i = 0; i < 4; ++i)
            #pragma unroll
            for (int j = 0; j < 4; ++j) {
                accRe[i][j] = __builtin_amdgcn_mfma_f32_16x16x32_bf16(fa[i], fb[j], accRe[i][j], 0, 0, 0);
                accIm[i][j] = __builtin_amdgcn_mfma_f32_16x16x32_bf16(fs[i], fb[j], accIm[i][j], 0, 0, 0);
            }
        __syncthreads();
    }

    // ---- epilogue: pdp[r][m] = (Re^2+Im^2)/2046^2 as bf16
    // C/D layout (m89): col = lane&15 (r), row = (lane>>4)*4 + q (m)
    const float inv = 1.0f / ((float)FFT_N * (float)FFT_N);
    #pragma unroll
    for (int i = 0; i < 4; ++i)
        #pragma unroll
        for (int j = 0; j < 4; ++j) {
            int m = m0 + wm + i * 16 + (lane >> 4) * 4;
            int r = r0 + wr + j * 16 + (lane & 15);
            #pragma unroll
            for (int q = 0; q < 4; ++q) {
                float re = accRe[i][j][q], im = accIm[i][j][q];
                pdp[(size_t)r * IN_N + (m + q)] = f2bf((re * re + im * im) * inv);
            }
        }
}

// ---------------------------------------------------------------------------
// Kernel 4: per-row-pair stats (symmetry: weight 2 for k=1..1022, 1 for 0,1023)
// delay = 1023*(1 - w0)  =>  |d_p - d_t|/2046 = 0.5*|w0_p - w0_t|
// ---------------------------------------------------------------------------
__device__ __forceinline__ float breduce(float v, float* red, int t, int op) {
    __syncthreads();
    red[t] = v;
    __syncthreads();
    for (int s = 128; s > 0; s >>= 1) {
        if (t < s) {
            float x = red[t], y = red[t + s];
            red[t] = (op == 0) ? (x + y) : (op == 1) ? fmaxf(x, y) : fminf(x, y);
        }
        __syncthreads();
    }
    return red[0];
}

__global__ __launch_bounds__(256) void row_stats_kernel(
    const u16* __restrict__ pdp,
    float* __restrict__ mse_rows, float* __restrict__ dd_rows) {

    __shared__ float red[256];
    const int r = blockIdx.x;
    const int t = threadIdx.x;
    const u16* pp = pdp + (size_t)r * IN_N;
    const u16* pt = pdp + (size_t)(NROWS + r) * IN_N;
    ushort4 up = *(const ushort4*)(pp + t * 4);
    ushort4 ut = *(const ushort4*)(pt + t * 4);
    float a[4] = {bf2f(up.x), bf2f(up.y), bf2f(up.z), bf2f(up.w)};
    float b[4] = {bf2f(ut.x), bf2f(ut.y), bf2f(ut.z), bf2f(ut.w)};

    float wsp = 0.f, wst = 0.f;
    float mxp = -1e30f, mnp = 1e30f, mxt = -1e30f, mnt = 1e30f;
    #pragma unroll
    for (int i = 0; i < 4; ++i) {
        int k = t * 4 + i;
        float wgt = (k == 0 || k == 1023) ? 1.f : 2.f;
        wsp += wgt * a[i];        wst += wgt * b[i];
        mxp = fmaxf(mxp, a[i]);   mnp = fminf(mnp, a[i]);
        mxt = fmaxf(mxt, b[i]);   mnt = fminf(mnt, b[i]);
    }
    float Ep  = breduce(wsp, red, t, 0);
    float Et  = breduce(wst, red, t, 0);
    float Mp  = breduce(mxp, red, t, 1);
    float mp_ = breduce(mnp, red, t, 2);
    float Mt  = breduce(mxt, red, t, 1);
    float mt_ = breduce(mnt, red, t, 2);

    float scp = (Ep < 1e-8f) ? 1.f : 1.f / Ep;
    float sct = (Et < 1e-8f) ? 1.f : 1.f / Et;
    float rngp = fmaxf(scp * (Mp - mp_), 1e-8f);
    float rngt = fmaxf(sct * (Mt - mt_), 1e-8f);
    float cfp = 10.f * scp / rngp;        // score_k = cfp * raw_pdp_k
    float cft = 10.f * sct / rngt;
    float smp = cfp * Mp;                 // max score
    float smt = cft * Mt;

    float zp = 0.f, zt = 0.f, ms = 0.f;
    #pragma unroll
    for (int i = 0; i < 4; ++i) {
        int k = t * 4 + i;
        float wgt = (k == 0 || k == 1023) ? 1.f : 2.f;
        zp += wgt * expf(cfp * a[i] - smp);
        zt += wgt * expf(cft * b[i] - smt);
        float d = a[i] * scp - b[i] * sct;
        ms += wgt * d * d;
    }
    float Zp  = breduce(zp, red, t, 0);
    float Zt  = breduce(zt, red, t, 0);
    float MSE = breduce(ms, red, t, 0);

    if (t == 0) {
        float w0p = expf(cfp * a[0] - smp) / Zp;   // k=0 lives in thread 0
        float w0t = expf(cft * b[0] - smt) / Zt;
        mse_rows[r] = MSE;
        dd_rows[r]  = 0.5f * fabsf(w0p - w0t);
    }
}

// ---------------------------------------------------------------------------
// Kernel 5: final scalar reduce.
// ---------------------------------------------------------------------------
__global__ __launch_bounds__(256) void final_kernel(
    const float* __restrict__ mse_rows, const float* __restrict__ dd_rows,
    float* __restrict__ out) {
    __shared__ float r1[256];
    __shared__ float r2[256];
    int t = threadIdx.x;
    float s1 = 0.f, s2 = 0.f;
    for (int r = t; r < NROWS; r += 256) { s1 += mse_rows[r]; s2 += dd_rows[r]; }
    r1[t] = s1; r2[t] = s2;
    __syncthreads();
    for (int s = 128; s > 0; s >>= 1) {
        if (t < s) { r1[t] += r1[t + s]; r2[t] += r2[t + s]; }
        __syncthreads();
    }
    if (t == 0) {
        float mse = r1[0] / ((float)NROWS * (float)FFT_N);
        float dl  = r2[0] / (float)NROWS;
        out[0] = 0.7f * mse + 0.3f * dl;
    }
}

// ---------------------------------------------------------------------------
extern "C" void kernel_launch(void* const* d_in, const int* in_sizes, int n_in,
                              void* d_out, int out_size, void* d_ws, size_t ws_size,
                              hipStream_t stream) {
    const float* pred = (const float*)d_in[0];
    const float* tgt  = (const float*)d_in[1];
    float* out = (float*)d_out;

    char* ws = (char*)d_ws;
    u16* Xh   = (u16*)ws;                                   // 32 MiB
    u16* Wch  = (u16*)(ws + (size_t)32 * 1024 * 1024);      //  2 MiB
    u16* Wcl  = (u16*)(ws + (size_t)34 * 1024 * 1024);      //  2 MiB
    u16* Wsh  = (u16*)(ws + (size_t)36 * 1024 * 1024);      //  2 MiB
    u16* Wsl  = (u16*)(ws + (size_t)38 * 1024 * 1024);      //  2 MiB
    u16* pdp  = (u16*)(ws + (size_t)40 * 1024 * 1024);      // 32 MiB
    float* mse_rows = (float*)(ws + (size_t)72 * 1024 * 1024);
    float* dd_rows  = mse_rows + NROWS;

    twiddle_kernel<<<1024, 256, 0, stream>>>(Wch, Wcl, Wsh, Wsl);
    convert_kernel<<<NTOT * IN_N / 4 / 256, 256, 0, stream>>>(pred, tgt, Xh);

    dim3 g(IN_N / BM, NTOT / BN);   // (8, 128)
    dft_pdp_mfma<<<g, 256, 0, stream>>>(Wch, Wcl, Wsh, Wsl, Xh, pdp);

    row_stats_kernel<<<NROWS, 256, 0, stream>>>(pdp, mse_rows, dd_rows);
    final_kernel<<<1, 256, 0, stream>>>(mse_rows, dd_rows, out);
}

// Round 3
// 167.258 us; speedup vs baseline: 5.4349x; 2.1090x over previous
//
#include <hip/hip_runtime.h>
#include <math.h>

#define IN_N   1024
#define NROWS  8192      // rows per tensor
#define NTOT   16384     // both tensors
#define FFT_N  2046

typedef unsigned short u16;
typedef __attribute__((ext_vector_type(8))) __bf16 bf16x8;
typedef __attribute__((ext_vector_type(4))) float  f32x4;

// ---- bf16 helpers (RTNE) --------------------------------------------------
__device__ __forceinline__ u16 f2bf(float f) {
    unsigned u = __builtin_bit_cast(unsigned, f);
    unsigned r = (u + 0x7fffu + ((u >> 16) & 1u)) >> 16;
    return (u16)r;
}
__device__ __forceinline__ float bf2f(u16 h) {
    unsigned u = ((unsigned)h) << 16;
    return __builtin_bit_cast(float, u);
}

// ---- async global->LDS, 16B per lane --------------------------------------
__device__ __forceinline__ void gload_lds16(const void* g, void* l) {
    __builtin_amdgcn_global_load_lds(
        (__attribute__((address_space(1))) void*)g,
        (__attribute__((address_space(3))) void*)l, 16, 0, 0);
}

// ---------------------------------------------------------------------------
// Kernel 1: twiddle tables (bf16 hi only — X's own bf16 rounding dominates).
// ---------------------------------------------------------------------------
__global__ void twiddle_kernel(u16* __restrict__ Wc, u16* __restrict__ Ws) {
    int k = blockIdx.x;
    int n0 = threadIdx.x * 4;
    const float c = 6.28318530717958647692f / 2046.0f;
    ushort4 oc, os;
    #pragma unroll
    for (int i = 0; i < 4; ++i) {
        int n = n0 + i;
        int m = (k * n) % FFT_N;
        float a = (float)m * c;
        float sv, cv;
        sincosf(a, &sv, &cv);
        ((u16*)&oc)[i] = f2bf(cv);
        ((u16*)&os)[i] = f2bf(sv);
    }
    size_t o = (size_t)k * IN_N + n0;
    *(ushort4*)(Wc + o) = oc;
    *(ushort4*)(Ws + o) = os;
}

// ---------------------------------------------------------------------------
// Kernel 2: convert X (pred ++ tgt) fp32 -> bf16 (RTNE).
// ---------------------------------------------------------------------------
__global__ __launch_bounds__(256) void convert_kernel(
    const float* __restrict__ pred, const float* __restrict__ tgt,
    u16* __restrict__ Xh) {
    size_t gid = (size_t)blockIdx.x * 256 + threadIdx.x;   // float4 index
    size_t e = gid * 4;
    const size_t half = (size_t)NROWS * IN_N;
    const float* s = (e < half) ? (pred + e) : (tgt + (e - half));
    float4 v = *(const float4*)s;
    ushort4 o;
    o.x = f2bf(v.x); o.y = f2bf(v.y); o.z = f2bf(v.z); o.w = f2bf(v.w);
    *(ushort4*)(Xh + e) = o;
}

// ---------------------------------------------------------------------------
// Kernel 3: MFMA DFT + |.|^2, K=1024, 128x128 tile, BK=32, 4 waves,
// double-buffered LDS (2-phase: STAGE(next) -> ds_read+MFMA(cur) -> barrier),
// XCD swizzle: each XCD owns r-block groups; the 8 m-blocks of one r-block
// are adjacent co-XCD so the X-tile is fetched into that L2 once.
// ---------------------------------------------------------------------------
#define BM 128
#define BN 128
#define BK 32
#define KTOT 1024

__global__ __launch_bounds__(256) void dft_pdp_mfma(
    const u16* __restrict__ Wc, const u16* __restrict__ Ws,
    const u16* __restrict__ Xh, u16* __restrict__ pdp) {

    __shared__ char ldsb[2][3 * 8192];   // 48 KB: {cos, sin, X} x dbuf

    // ---- XCD-aware decode (1024 blocks, 8 XCDs, bijective)
    const int bid  = blockIdx.x;
    const int xcd  = bid & 7;
    const int slot = bid >> 3;                 // 0..127 within XCD
    const int m0 = (slot & 7) * BM;            // m-block fastest within XCD
    const int r0 = (xcd + ((slot >> 3) << 3)) * BN;

    const int t    = threadIdx.x;
    const int w    = t >> 6;
    const int lane = t & 63;
    const int wm = (w & 1) * 64;
    const int wr = (w >> 1) * 64;
    const int lr = lane & 15;            // frag row
    const int lkb = (lane >> 4) * 16;    // frag k byte-offset (8 bf16)

    const char* gA = (const char*)Wc + (size_t)m0 * (IN_N * 2);
    const char* gS = (const char*)Ws + (size_t)m0 * (IN_N * 2);
    const char* gX = (const char*)Xh + (size_t)r0 * (IN_N * 2);

    f32x4 accRe[4][4], accIm[4][4];
    #pragma unroll
    for (int i = 0; i < 4; ++i)
        #pragma unroll
        for (int j = 0; j < 4; ++j)
            #pragma unroll
            for (int q = 0; q < 4; ++q) { accRe[i][j][q] = 0.f; accIm[i][j][q] = 0.f; }

    auto STAGE = [&](int buf, int kc) {
        #pragma unroll
        for (int it = 0; it < 2; ++it) {
            int off = it * 4096 + w * 1024 + lane * 16;  // byte off in 8KB tile
            int row = off >> 6;                          // 64 B per row
            int cb  = off & 63;
            size_t gofs = (size_t)row * 2048 + (size_t)kc * 2 + cb;
            char* la = &ldsb[buf][0]         + it * 4096 + w * 1024; // wave-uniform
            char* ls = &ldsb[buf][0] + 8192  + it * 4096 + w * 1024;
            char* lx = &ldsb[buf][0] + 16384 + it * 4096 + w * 1024;
            gload_lds16(gA + gofs, la);
            gload_lds16(gS + gofs, ls);
            gload_lds16(gX + gofs, lx);
        }
    };

    STAGE(0, 0);
    __syncthreads();          // drains vmcnt(0) before first ds_read

    int cur = 0;
    for (int kc = 0; kc < KTOT; kc += BK) {
        if (kc + BK < KTOT) STAGE(cur ^ 1, kc + BK);   // prefetch overlaps MFMA

        const char* base = &ldsb[cur][0];
        bf16x8 fb[4];
        #pragma unroll
        for (int j = 0; j < 4; ++j)
            fb[j] = *(const bf16x8*)(base + 16384 + (wr + j * 16 + lr) * 64 + lkb);
        #pragma unroll
        for (int i = 0; i < 4; ++i) {
            bf16x8 fa = *(const bf16x8*)(base +        (wm + i * 16 + lr) * 64 + lkb);
            bf16x8 fs = *(const bf16x8*)(base + 8192 + (wm + i * 16 + lr) * 64 + lkb);
            #pragma unroll
            for (int j = 0; j < 4; ++j) {
                accRe[i][j] = __builtin_amdgcn_mfma_f32_16x16x32_bf16(fa, fb[j], accRe[i][j], 0, 0, 0);
                accIm[i][j] = __builtin_amdgcn_mfma_f32_16x16x32_bf16(fs, fb[j], accIm[i][j], 0, 0, 0);
            }
        }
        __syncthreads();      // next buffer staged + reads of cur done
        cur ^= 1;
    }

    // ---- epilogue: pdp[r][m] = (Re^2+Im^2)/2046^2 as bf16
    // C/D layout (m89): col = lane&15 (r), row = (lane>>4)*4 + q (m)
    const float inv = 1.0f / ((float)FFT_N * (float)FFT_N);
    #pragma unroll
    for (int i = 0; i < 4; ++i)
        #pragma unroll
        for (int j = 0; j < 4; ++j) {
            int m = m0 + wm + i * 16 + (lane >> 4) * 4;
            int r = r0 + wr + j * 16 + (lane & 15);
            #pragma unroll
            for (int q = 0; q < 4; ++q) {
                float re = accRe[i][j][q], im = accIm[i][j][q];
                pdp[(size_t)r * IN_N + (m + q)] = f2bf((re * re + im * im) * inv);
            }
        }
}

// ---------------------------------------------------------------------------
// Kernel 4: per-row-pair stats (symmetry: weight 2 for k=1..1022, 1 for 0,1023)
// delay = 1023*(1 - w0)  =>  |d_p - d_t|/2046 = 0.5*|w0_p - w0_t|
// ---------------------------------------------------------------------------
__device__ __forceinline__ float breduce(float v, float* red, int t, int op) {
    __syncthreads();
    red[t] = v;
    __syncthreads();
    for (int s = 128; s > 0; s >>= 1) {
        if (t < s) {
            float x = red[t], y = red[t + s];
            red[t] = (op == 0) ? (x + y) : (op == 1) ? fmaxf(x, y) : fminf(x, y);
        }
        __syncthreads();
    }
    return red[0];
}

__global__ __launch_bounds__(256) void row_stats_kernel(
    const u16* __restrict__ pdp,
    float* __restrict__ mse_rows, float* __restrict__ dd_rows) {

    __shared__ float red[256];
    const int r = blockIdx.x;
    const int t = threadIdx.x;
    const u16* pp = pdp + (size_t)r * IN_N;
    const u16* pt = pdp + (size_t)(NROWS + r) * IN_N;
    ushort4 up = *(const ushort4*)(pp + t * 4);
    ushort4 ut = *(const ushort4*)(pt + t * 4);
    float a[4] = {bf2f(up.x), bf2f(up.y), bf2f(up.z), bf2f(up.w)};
    float b[4] = {bf2f(ut.x), bf2f(ut.y), bf2f(ut.z), bf2f(ut.w)};

    float wsp = 0.f, wst = 0.f;
    float mxp = -1e30f, mnp = 1e30f, mxt = -1e30f, mnt = 1e30f;
    #pragma unroll
    for (int i = 0; i < 4; ++i) {
        int k = t * 4 + i;
        float wgt = (k == 0 || k == 1023) ? 1.f : 2.f;
        wsp += wgt * a[i];        wst += wgt * b[i];
        mxp = fmaxf(mxp, a[i]);   mnp = fminf(mnp, a[i]);
        mxt = fmaxf(mxt, b[i]);   mnt = fminf(mnt, b[i]);
    }
    float Ep  = breduce(wsp, red, t, 0);
    float Et  = breduce(wst, red, t, 0);
    float Mp  = breduce(mxp, red, t, 1);
    float mp_ = breduce(mnp, red, t, 2);
    float Mt  = breduce(mxt, red, t, 1);
    float mt_ = breduce(mnt, red, t, 2);

    float scp = (Ep < 1e-8f) ? 1.f : 1.f / Ep;
    float sct = (Et < 1e-8f) ? 1.f : 1.f / Et;
    float rngp = fmaxf(scp * (Mp - mp_), 1e-8f);
    float rngt = fmaxf(sct * (Mt - mt_), 1e-8f);
    float cfp = 10.f * scp / rngp;        // score_k = cfp * raw_pdp_k
    float cft = 10.f * sct / rngt;
    float smp = cfp * Mp;                 // max score
    float smt = cft * Mt;

    float zp = 0.f, zt = 0.f, ms = 0.f;
    #pragma unroll
    for (int i = 0; i < 4; ++i) {
        int k = t * 4 + i;
        float wgt = (k == 0 || k == 1023) ? 1.f : 2.f;
        zp += wgt * expf(cfp * a[i] - smp);
        zt += wgt * expf(cft * b[i] - smt);
        float d = a[i] * scp - b[i] * sct;
        ms += wgt * d * d;
    }
    float Zp  = breduce(zp, red, t, 0);
    float Zt  = breduce(zt, red, t, 0);
    float MSE = breduce(ms, red, t, 0);

    if (t == 0) {
        float w0p = expf(cfp * a[0] - smp) / Zp;   // k=0 lives in thread 0
        float w0t = expf(cft * b[0] - smt) / Zt;
        mse_rows[r] = MSE;
        dd_rows[r]  = 0.5f * fabsf(w0p - w0t);
    }
}

// ---------------------------------------------------------------------------
// Kernel 5: final scalar reduce.
// ---------------------------------------------------------------------------
__global__ __launch_bounds__(256) void final_kernel(
    const float* __restrict__ mse_rows, const float* __restrict__ dd_rows,
    float* __restrict__ out) {
    __shared__ float r1[256];
    __shared__ float r2[256];
    int t = threadIdx.x;
    float s1 = 0.f, s2 = 0.f;
    for (int r = t; r < NROWS; r += 256) { s1 += mse_rows[r]; s2 += dd_rows[r]; }
    r1[t] = s1; r2[t] = s2;
    __syncthreads();
    for (int s = 128; s > 0; s >>= 1) {
        if (t < s) { r1[t] += r1[t + s]; r2[t] += r2[t + s]; }
        __syncthreads();
    }
    if (t == 0) {
        float mse = r1[0] / ((float)NROWS * (float)FFT_N);
        float dl  = r2[0] / (float)NROWS;
        out[0] = 0.7f * mse + 0.3f * dl;
    }
}

// ---------------------------------------------------------------------------
extern "C" void kernel_launch(void* const* d_in, const int* in_sizes, int n_in,
                              void* d_out, int out_size, void* d_ws, size_t ws_size,
                              hipStream_t stream) {
    const float* pred = (const float*)d_in[0];
    const float* tgt  = (const float*)d_in[1];
    float* out = (float*)d_out;

    char* ws = (char*)d_ws;
    u16* Xh   = (u16*)ws;                                   // 32 MiB
    u16* Wch  = (u16*)(ws + (size_t)32 * 1024 * 1024);      //  2 MiB
    u16* Wsh  = (u16*)(ws + (size_t)34 * 1024 * 1024);      //  2 MiB
    u16* pdp  = (u16*)(ws + (size_t)40 * 1024 * 1024);      // 32 MiB
    float* mse_rows = (float*)(ws + (size_t)72 * 1024 * 1024);
    float* dd_rows  = mse_rows + NROWS;

    twiddle_kernel<<<1024, 256, 0, stream>>>(Wch, Wsh);
    convert_kernel<<<NTOT * IN_N / 4 / 256, 256, 0, stream>>>(pred, tgt, Xh);

    dft_pdp_mfma<<<1024, 256, 0, stream>>>(Wch, Wsh, Xh, pdp);

    row_stats_kernel<<<NROWS, 256, 0, stream>>>(pdp, mse_rows, dd_rows);
    final_kernel<<<1, 256, 0, stream>>>(mse_rows, dd_rows, out);
}

// Round 4
// 140.267 us; speedup vs baseline: 6.4807x; 1.1924x over previous
//
#include <hip/hip_runtime.h>
#include <math.h>

#define IN_N   1024
#define NROWS  8192      // rows per tensor
#define NTOT   16384     // both tensors
#define FFT_N  2046

typedef unsigned short u16;
typedef __attribute__((ext_vector_type(8))) __bf16 bf16x8;
typedef __attribute__((ext_vector_type(4))) float  f32x4;

// ---- bf16 helpers (RTNE) --------------------------------------------------
__device__ __forceinline__ u16 f2bf(float f) {
    unsigned u = __builtin_bit_cast(unsigned, f);
    unsigned r = (u + 0x7fffu + ((u >> 16) & 1u)) >> 16;
    return (u16)r;
}
__device__ __forceinline__ float bf2f(u16 h) {
    unsigned u = ((unsigned)h) << 16;
    return __builtin_bit_cast(float, u);
}

// ---- async global->LDS, 16B per lane (dest = wave-uniform base + lane*16) --
__device__ __forceinline__ void gload_lds16(const void* g, void* l) {
    __builtin_amdgcn_global_load_lds(
        (__attribute__((address_space(1))) void*)g,
        (__attribute__((address_space(3))) void*)l, 16, 0, 0);
}

// ---------------------------------------------------------------------------
// Kernel 1: twiddle tables (bf16 hi only — X's own bf16 rounding dominates).
// ---------------------------------------------------------------------------
__global__ void twiddle_kernel(u16* __restrict__ Wc, u16* __restrict__ Ws) {
    int k = blockIdx.x;
    int n0 = threadIdx.x * 4;
    const float c = 6.28318530717958647692f / 2046.0f;
    ushort4 oc, os;
    #pragma unroll
    for (int i = 0; i < 4; ++i) {
        int n = n0 + i;
        int m = (k * n) % FFT_N;
        float a = (float)m * c;
        float sv, cv;
        sincosf(a, &sv, &cv);
        ((u16*)&oc)[i] = f2bf(cv);
        ((u16*)&os)[i] = f2bf(sv);
    }
    size_t o = (size_t)k * IN_N + n0;
    *(ushort4*)(Wc + o) = oc;
    *(ushort4*)(Ws + o) = os;
}

// ---------------------------------------------------------------------------
// Kernel 2: convert X (pred ++ tgt) fp32 -> bf16 (RTNE).
// ---------------------------------------------------------------------------
__global__ __launch_bounds__(256) void convert_kernel(
    const float* __restrict__ pred, const float* __restrict__ tgt,
    u16* __restrict__ Xh) {
    size_t gid = (size_t)blockIdx.x * 256 + threadIdx.x;   // float4 index
    size_t e = gid * 4;
    const size_t half = (size_t)NROWS * IN_N;
    const float* s = (e < half) ? (pred + e) : (tgt + (e - half));
    float4 v = *(const float4*)s;
    ushort4 o;
    o.x = f2bf(v.x); o.y = f2bf(v.y); o.z = f2bf(v.z); o.w = f2bf(v.w);
    *(ushort4*)(Xh + e) = o;
}

// ---------------------------------------------------------------------------
// Kernel 3: MFMA DFT + |.|^2, counted-vmcnt multi-phase schedule (T3+T4+T5).
// Tile 128(m) x 256(r), 8 waves (2m x 4r), BK=32, 4 LDS buffers (128 KiB),
// prefetch depth 3, vmcnt(8) boundaries (never 0 in main loop).
// Per K-tile 2 phases x 16 MFMA.  Bank swizzle: slot ^= row&3 (both sides).
// ---------------------------------------------------------------------------
#define BM 128
#define BN 256
#define BK 32
#define NKT 32     // K tiles = 1024/32

__global__ __launch_bounds__(512, 2) void dft_pdp_mfma(
    const u16* __restrict__ Wc, const u16* __restrict__ Ws,
    const u16* __restrict__ Xh, u16* __restrict__ pdp) {

    // per buffer: A(cos) 8KB | S(sin) 8KB | X 16KB  = 32KB; x4 buffers
    __shared__ __align__(16) char lds[4][32768];

    // ---- XCD-aware decode (512 blocks, 8 XCDs, bijective)
    const int bid  = blockIdx.x;
    const int xcd  = bid & 7;
    const int slot = bid >> 3;                  // 0..63
    const int m0 = (slot & 7) * BM;
    const int r0 = (xcd * 8 + (slot >> 3)) * BN;

    const int t    = threadIdx.x;
    const int w    = t >> 6;                    // 0..7
    const int lane = t & 63;
    const int wm = (w & 1) * 64;                // wave m offset
    const int wr = (w >> 1) * 64;               // wave r offset
    const int lr = lane & 15;                   // frag row within 16
    // read-side swizzled k-chunk byte offset (per-lane constant):
    const int rdoff = (((lane >> 4) ^ (lane & 3)) << 4);

    // staging source (per-thread constants); source col pre-swizzled so that
    // linear gload_lds dest + swizzled ds_read compose to identity (rule 21)
    const int srow  = t >> 2;                   // 0..127
    const int sslot = (t & 3) ^ (srow & 3);
    const size_t aOfs  = (size_t)(m0 + srow) * 2048 + sslot * 16;
    const size_t xOfs0 = (size_t)(r0 + srow) * 2048 + sslot * 16;
    const size_t xOfs1 = (size_t)(r0 + 128 + srow) * 2048 + sslot * 16;
    const int woff = w << 10;                   // wave-uniform LDS base part

    f32x4 accRe[4][4], accIm[4][4];
    #pragma unroll
    for (int i = 0; i < 4; ++i)
        #pragma unroll
        for (int j = 0; j < 4; ++j)
            #pragma unroll
            for (int q = 0; q < 4; ++q) { accRe[i][j][q] = 0.f; accIm[i][j][q] = 0.f; }

    #define STAGE_A(buf, kt) do { \
        gload_lds16((const char*)Wc + aOfs + (size_t)(kt) * 64, &lds[buf][0] + woff); \
        gload_lds16((const char*)Ws + aOfs + (size_t)(kt) * 64, &lds[buf][0] + 8192 + woff); \
    } while (0)
    #define STAGE_X(buf, kt) do { \
        gload_lds16((const char*)Xh + xOfs0 + (size_t)(kt) * 64, &lds[buf][0] + 16384 + woff); \
        gload_lds16((const char*)Xh + xOfs1 + (size_t)(kt) * 64, &lds[buf][0] + 24576 + woff); \
    } while (0)

    // ---- prologue: stage tiles 0,1,2 (12 issues); wait oldest 4
    STAGE_A(0, 0); STAGE_X(0, 0);
    STAGE_A(1, 1); STAGE_X(1, 1);
    STAGE_A(2, 2); STAGE_X(2, 2);
    asm volatile("s_waitcnt vmcnt(8)" ::: "memory");
    __builtin_amdgcn_s_barrier();

    for (int kt = 0; kt < NKT; ++kt) {
        const int  buf = kt & 3;
        const char* bA = &lds[buf][0];
        const char* bS = &lds[buf][0] + 8192;
        const char* bX = &lds[buf][0] + 16384;
        const bool st  = (kt + 3) < NKT;
        const int  sb  = (kt + 3) & 3;

        // ================= phase A =================
        bf16x8 fb[4], fa0, fa1, fs0, fs1;
        #pragma unroll
        for (int j = 0; j < 4; ++j)
            fb[j] = *(const bf16x8*)(bX + (wr + j * 16 + lr) * 64 + rdoff);
        fa0 = *(const bf16x8*)(bA + (wm +  0 + lr) * 64 + rdoff);
        fa1 = *(const bf16x8*)(bA + (wm + 16 + lr) * 64 + rdoff);
        fs0 = *(const bf16x8*)(bS + (wm +  0 + lr) * 64 + rdoff);
        fs1 = *(const bf16x8*)(bS + (wm + 16 + lr) * 64 + rdoff);
        if (st) STAGE_A(sb, kt + 3);
        __builtin_amdgcn_s_barrier();
        asm volatile("s_waitcnt lgkmcnt(0)" ::: "memory");
        __builtin_amdgcn_sched_barrier(0);
        __builtin_amdgcn_s_setprio(1);
        #pragma unroll
        for (int j = 0; j < 4; ++j) {
            accRe[0][j] = __builtin_amdgcn_mfma_f32_16x16x32_bf16(fa0, fb[j], accRe[0][j], 0, 0, 0);
            accIm[0][j] = __builtin_amdgcn_mfma_f32_16x16x32_bf16(fs0, fb[j], accIm[0][j], 0, 0, 0);
        }
        #pragma unroll
        for (int j = 0; j < 4; ++j) {
            accRe[1][j] = __builtin_amdgcn_mfma_f32_16x16x32_bf16(fa1, fb[j], accRe[1][j], 0, 0, 0);
            accIm[1][j] = __builtin_amdgcn_mfma_f32_16x16x32_bf16(fs1, fb[j], accIm[1][j], 0, 0, 0);
        }
        __builtin_amdgcn_s_setprio(0);
        __builtin_amdgcn_s_barrier();

        // ================= phase B =================
        bf16x8 fa2, fa3, fs2, fs3;
        fa2 = *(const bf16x8*)(bA + (wm + 32 + lr) * 64 + rdoff);
        fa3 = *(const bf16x8*)(bA + (wm + 48 + lr) * 64 + rdoff);
        fs2 = *(const bf16x8*)(bS + (wm + 32 + lr) * 64 + rdoff);
        fs3 = *(const bf16x8*)(bS + (wm + 48 + lr) * 64 + rdoff);
        if (st) STAGE_X(sb, kt + 3);
        __builtin_amdgcn_s_barrier();
        asm volatile("s_waitcnt lgkmcnt(0)" ::: "memory");
        __builtin_amdgcn_sched_barrier(0);
        __builtin_amdgcn_s_setprio(1);
        #pragma unroll
        for (int j = 0; j < 4; ++j) {
            accRe[2][j] = __builtin_amdgcn_mfma_f32_16x16x32_bf16(fa2, fb[j], accRe[2][j], 0, 0, 0);
            accIm[2][j] = __builtin_amdgcn_mfma_f32_16x16x32_bf16(fs2, fb[j], accIm[2][j], 0, 0, 0);
        }
        #pragma unroll
        for (int j = 0; j < 4; ++j) {
            accRe[3][j] = __builtin_amdgcn_mfma_f32_16x16x32_bf16(fa3, fb[j], accRe[3][j], 0, 0, 0);
            accIm[3][j] = __builtin_amdgcn_mfma_f32_16x16x32_bf16(fs3, fb[j], accIm[3][j], 0, 0, 0);
        }
        __builtin_amdgcn_s_setprio(0);
        // ---- tile boundary: counted vmcnt (oldest staged tile must be done)
        if (kt <= 28)      asm volatile("s_waitcnt vmcnt(8)" ::: "memory");
        else if (kt == 29) asm volatile("s_waitcnt vmcnt(4)" ::: "memory");
        else if (kt == 30) asm volatile("s_waitcnt vmcnt(0)" ::: "memory");
        __builtin_amdgcn_s_barrier();
    }
    #undef STAGE_A
    #undef STAGE_X

    // ---- epilogue: pdp[r][m..m+3] = (Re^2+Im^2)/2046^2 as bf16 (8B stores)
    // C/D layout (m89): col = lane&15 (r), row = (lane>>4)*4 + q (m)
    const float inv = 1.0f / ((float)FFT_N * (float)FFT_N);
    #pragma unroll
    for (int i = 0; i < 4; ++i)
        #pragma unroll
        for (int j = 0; j < 4; ++j) {
            int m = m0 + wm + i * 16 + (lane >> 4) * 4;
            int r = r0 + wr + j * 16 + (lane & 15);
            ushort4 o;
            #pragma unroll
            for (int q = 0; q < 4; ++q) {
                float re = accRe[i][j][q], im = accIm[i][j][q];
                ((u16*)&o)[q] = f2bf((re * re + im * im) * inv);
            }
            *(ushort4*)(pdp + (size_t)r * IN_N + m) = o;
        }
}

// ---------------------------------------------------------------------------
// Kernel 4: per-row-pair stats (symmetry: weight 2 for k=1..1022, 1 for 0,1023)
// delay = 1023*(1 - w0)  =>  |d_p - d_t|/2046 = 0.5*|w0_p - w0_t|
// ---------------------------------------------------------------------------
__device__ __forceinline__ float breduce(float v, float* red, int t, int op) {
    __syncthreads();
    red[t] = v;
    __syncthreads();
    for (int s = 128; s > 0; s >>= 1) {
        if (t < s) {
            float x = red[t], y = red[t + s];
            red[t] = (op == 0) ? (x + y) : (op == 1) ? fmaxf(x, y) : fminf(x, y);
        }
        __syncthreads();
    }
    return red[0];
}

__global__ __launch_bounds__(256) void row_stats_kernel(
    const u16* __restrict__ pdp,
    float* __restrict__ mse_rows, float* __restrict__ dd_rows) {

    __shared__ float red[256];
    const int r = blockIdx.x;
    const int t = threadIdx.x;
    const u16* pp = pdp + (size_t)r * IN_N;
    const u16* pt = pdp + (size_t)(NROWS + r) * IN_N;
    ushort4 up = *(const ushort4*)(pp + t * 4);
    ushort4 ut = *(const ushort4*)(pt + t * 4);
    float a[4] = {bf2f(up.x), bf2f(up.y), bf2f(up.z), bf2f(up.w)};
    float b[4] = {bf2f(ut.x), bf2f(ut.y), bf2f(ut.z), bf2f(ut.w)};

    float wsp = 0.f, wst = 0.f;
    float mxp = -1e30f, mnp = 1e30f, mxt = -1e30f, mnt = 1e30f;
    #pragma unroll
    for (int i = 0; i < 4; ++i) {
        int k = t * 4 + i;
        float wgt = (k == 0 || k == 1023) ? 1.f : 2.f;
        wsp += wgt * a[i];        wst += wgt * b[i];
        mxp = fmaxf(mxp, a[i]);   mnp = fminf(mnp, a[i]);
        mxt = fmaxf(mxt, b[i]);   mnt = fminf(mnt, b[i]);
    }
    float Ep  = breduce(wsp, red, t, 0);
    float Et  = breduce(wst, red, t, 0);
    float Mp  = breduce(mxp, red, t, 1);
    float mp_ = breduce(mnp, red, t, 2);
    float Mt  = breduce(mxt, red, t, 1);
    float mt_ = breduce(mnt, red, t, 2);

    float scp = (Ep < 1e-8f) ? 1.f : 1.f / Ep;
    float sct = (Et < 1e-8f) ? 1.f : 1.f / Et;
    float rngp = fmaxf(scp * (Mp - mp_), 1e-8f);
    float rngt = fmaxf(sct * (Mt - mt_), 1e-8f);
    float cfp = 10.f * scp / rngp;        // score_k = cfp * raw_pdp_k
    float cft = 10.f * sct / rngt;
    float smp = cfp * Mp;                 // max score
    float smt = cft * Mt;

    float zp = 0.f, zt = 0.f, ms = 0.f;
    #pragma unroll
    for (int i = 0; i < 4; ++i) {
        int k = t * 4 + i;
        float wgt = (k == 0 || k == 1023) ? 1.f : 2.f;
        zp += wgt * expf(cfp * a[i] - smp);
        zt += wgt * expf(cft * b[i] - smt);
        float d = a[i] * scp - b[i] * sct;
        ms += wgt * d * d;
    }
    float Zp  = breduce(zp, red, t, 0);
    float Zt  = breduce(zt, red, t, 0);
    float MSE = breduce(ms, red, t, 0);

    if (t == 0) {
        float w0p = expf(cfp * a[0] - smp) / Zp;   // k=0 lives in thread 0
        float w0t = expf(cft * b[0] - smt) / Zt;
        mse_rows[r] = MSE;
        dd_rows[r]  = 0.5f * fabsf(w0p - w0t);
    }
}

// ---------------------------------------------------------------------------
// Kernel 5: final scalar reduce.
// ---------------------------------------------------------------------------
__global__ __launch_bounds__(256) void final_kernel(
    const float* __restrict__ mse_rows, const float* __restrict__ dd_rows,
    float* __restrict__ out) {
    __shared__ float r1[256];
    __shared__ float r2[256];
    int t = threadIdx.x;
    float s1 = 0.f, s2 = 0.f;
    for (int r = t; r < NROWS; r += 256) { s1 += mse_rows[r]; s2 += dd_rows[r]; }
    r1[t] = s1; r2[t] = s2;
    __syncthreads();
    for (int s = 128; s > 0; s >>= 1) {
        if (t < s) { r1[t] += r1[t + s]; r2[t] += r2[t + s]; }
        __syncthreads();
    }
    if (t == 0) {
        float mse = r1[0] / ((float)NROWS * (float)FFT_N);
        float dl  = r2[0] / (float)NROWS;
        out[0] = 0.7f * mse + 0.3f * dl;
    }
}

// ---------------------------------------------------------------------------
extern "C" void kernel_launch(void* const* d_in, const int* in_sizes, int n_in,
                              void* d_out, int out_size, void* d_ws, size_t ws_size,
                              hipStream_t stream) {
    const float* pred = (const float*)d_in[0];
    const float* tgt  = (const float*)d_in[1];
    float* out = (float*)d_out;

    char* ws = (char*)d_ws;
    u16* Xh   = (u16*)ws;                                   // 32 MiB
    u16* Wch  = (u16*)(ws + (size_t)32 * 1024 * 1024);      //  2 MiB
    u16* Wsh  = (u16*)(ws + (size_t)34 * 1024 * 1024);      //  2 MiB
    u16* pdp  = (u16*)(ws + (size_t)40 * 1024 * 1024);      // 32 MiB
    float* mse_rows = (float*)(ws + (size_t)72 * 1024 * 1024);
    float* dd_rows  = mse_rows + NROWS;

    twiddle_kernel<<<1024, 256, 0, stream>>>(Wch, Wsh);
    convert_kernel<<<NTOT * IN_N / 4 / 256, 256, 0, stream>>>(pred, tgt, Xh);

    dft_pdp_mfma<<<512, 512, 0, stream>>>(Wch, Wsh, Xh, pdp);

    row_stats_kernel<<<NROWS, 256, 0, stream>>>(pdp, mse_rows, dd_rows);
    final_kernel<<<1, 256, 0, stream>>>(mse_rows, dd_rows, out);
}

// Round 5
// 138.674 us; speedup vs baseline: 6.5552x; 1.0115x over previous
//
#include <hip/hip_runtime.h>
#include <math.h>

#define IN_N   1024
#define NROWS  8192      // rows per tensor
#define NTOT   16384     // both tensors
#define FFT_N  2046

typedef unsigned short u16;
typedef __attribute__((ext_vector_type(8))) __bf16 bf16x8;
typedef __attribute__((ext_vector_type(4))) float  f32x4;

// ---- bf16 helpers (RTNE) --------------------------------------------------
__device__ __forceinline__ u16 f2bf(float f) {
    unsigned u = __builtin_bit_cast(unsigned, f);
    unsigned r = (u + 0x7fffu + ((u >> 16) & 1u)) >> 16;
    return (u16)r;
}
__device__ __forceinline__ float bf2f(u16 h) {
    unsigned u = ((unsigned)h) << 16;
    return __builtin_bit_cast(float, u);
}

// ---- async global->LDS, 16B per lane (dest = wave-uniform base + lane*16) --
__device__ __forceinline__ void gload_lds16(const void* g, void* l) {
    __builtin_amdgcn_global_load_lds(
        (__attribute__((address_space(1))) void*)g,
        (__attribute__((address_space(3))) void*)l, 16, 0, 0);
}

// ---------------------------------------------------------------------------
// Kernel 1: twiddle tables (bf16 hi only — X's own bf16 rounding dominates).
// ---------------------------------------------------------------------------
__global__ void twiddle_kernel(u16* __restrict__ Wc, u16* __restrict__ Ws) {
    int k = blockIdx.x;
    int n0 = threadIdx.x * 4;
    const float c = 6.28318530717958647692f / 2046.0f;
    ushort4 oc, os;
    #pragma unroll
    for (int i = 0; i < 4; ++i) {
        int n = n0 + i;
        int m = (k * n) % FFT_N;
        float a = (float)m * c;
        float sv, cv;
        sincosf(a, &sv, &cv);
        ((u16*)&oc)[i] = f2bf(cv);
        ((u16*)&os)[i] = f2bf(sv);
    }
    size_t o = (size_t)k * IN_N + n0;
    *(ushort4*)(Wc + o) = oc;
    *(ushort4*)(Ws + o) = os;
}

// ---------------------------------------------------------------------------
// Kernel 2: convert X (pred ++ tgt) fp32 -> bf16 (RTNE).
// ---------------------------------------------------------------------------
__global__ __launch_bounds__(256) void convert_kernel(
    const float* __restrict__ pred, const float* __restrict__ tgt,
    u16* __restrict__ Xh) {
    size_t gid = (size_t)blockIdx.x * 256 + threadIdx.x;   // float4 index
    size_t e = gid * 4;
    const size_t half = (size_t)NROWS * IN_N;
    const float* s = (e < half) ? (pred + e) : (tgt + (e - half));
    float4 v = *(const float4*)s;
    ushort4 o;
    o.x = f2bf(v.x); o.y = f2bf(v.y); o.z = f2bf(v.z); o.w = f2bf(v.w);
    *(ushort4*)(Xh + e) = o;
}

// ---------------------------------------------------------------------------
// Kernel 3: MFMA DFT + |.|^2, counted-vmcnt multi-phase schedule (T3+T4+T5).
// Tile 128(m) x 256(r), 8 waves (2m x 4r), BK=32, 4 LDS buffers (128 KiB),
// prefetch depth 3, vmcnt(8) boundaries (never 0 in main loop).
// T2 swizzle (CORRECTED): quad = (row*4 + slot) mod 8 only exposes row bit 0
// at 64B row stride, so the swizzle must inject row bits 1-2:
//   slot ^= (row>>1)&3   (R4's row&3 was a no-op on conflicts — measured).
// ---------------------------------------------------------------------------
#define BM 128
#define BN 256
#define BK 32
#define NKT 32     // K tiles = 1024/32

__global__ __launch_bounds__(512, 2) void dft_pdp_mfma(
    const u16* __restrict__ Wc, const u16* __restrict__ Ws,
    const u16* __restrict__ Xh, u16* __restrict__ pdp) {

    // per buffer: A(cos) 8KB | S(sin) 8KB | X 16KB  = 32KB; x4 buffers
    __shared__ __align__(16) char lds[4][32768];

    // ---- XCD-aware decode (512 blocks, 8 XCDs, bijective)
    const int bid  = blockIdx.x;
    const int xcd  = bid & 7;
    const int slot = bid >> 3;                  // 0..63
    const int m0 = (slot & 7) * BM;
    const int r0 = (xcd * 8 + (slot >> 3)) * BN;

    const int t    = threadIdx.x;
    const int w    = t >> 6;                    // 0..7
    const int lane = t & 63;
    const int wm = (w & 1) * 64;                // wave m offset
    const int wr = (w >> 1) * 64;               // wave r offset
    const int lr = lane & 15;                   // frag row within 16
    // read-side swizzled k-chunk byte offset: slot = g ^ ((row>>1)&3),
    // row bits 1-2 == lane bits 1-2 (wm, i*16, wr, j*16 don't touch them)
    const int rdoff = (((lane >> 4) ^ ((lane >> 1) & 3)) << 4);

    // staging source pre-swizzle: thread t writes LDS row t>>2, slot t&3;
    // source col slot = (t&3) ^ ((row>>1)&3) = (t&3) ^ ((t>>3)&3)  (rule 21)
    const int srow  = t >> 2;                   // 0..127
    const int sslot = (t & 3) ^ ((t >> 3) & 3);
    const size_t aOfs  = (size_t)(m0 + srow) * 2048 + sslot * 16;
    const size_t xOfs0 = (size_t)(r0 + srow) * 2048 + sslot * 16;
    const size_t xOfs1 = (size_t)(r0 + 128 + srow) * 2048 + sslot * 16;
    const int woff = w << 10;                   // wave-uniform LDS base part

    f32x4 accRe[4][4], accIm[4][4];
    #pragma unroll
    for (int i = 0; i < 4; ++i)
        #pragma unroll
        for (int j = 0; j < 4; ++j)
            #pragma unroll
            for (int q = 0; q < 4; ++q) { accRe[i][j][q] = 0.f; accIm[i][j][q] = 0.f; }

    #define STAGE_A(buf, kt) do { \
        gload_lds16((const char*)Wc + aOfs + (size_t)(kt) * 64, &lds[buf][0] + woff); \
        gload_lds16((const char*)Ws + aOfs + (size_t)(kt) * 64, &lds[buf][0] + 8192 + woff); \
    } while (0)
    #define STAGE_X(buf, kt) do { \
        gload_lds16((const char*)Xh + xOfs0 + (size_t)(kt) * 64, &lds[buf][0] + 16384 + woff); \
        gload_lds16((const char*)Xh + xOfs1 + (size_t)(kt) * 64, &lds[buf][0] + 24576 + woff); \
    } while (0)

    // ---- prologue: stage tiles 0,1,2 (12 issues); wait oldest 4
    STAGE_A(0, 0); STAGE_X(0, 0);
    STAGE_A(1, 1); STAGE_X(1, 1);
    STAGE_A(2, 2); STAGE_X(2, 2);
    asm volatile("s_waitcnt vmcnt(8)" ::: "memory");
    __builtin_amdgcn_s_barrier();

    for (int kt = 0; kt < NKT; ++kt) {
        const int  buf = kt & 3;
        const char* bA = &lds[buf][0];
        const char* bS = &lds[buf][0] + 8192;
        const char* bX = &lds[buf][0] + 16384;
        const bool st  = (kt + 3) < NKT;
        const int  sb  = (kt + 3) & 3;

        // ================= phase A =================
        bf16x8 fb[4], fa0, fa1, fs0, fs1;
        #pragma unroll
        for (int j = 0; j < 4; ++j)
            fb[j] = *(const bf16x8*)(bX + (wr + j * 16 + lr) * 64 + rdoff);
        fa0 = *(const bf16x8*)(bA + (wm +  0 + lr) * 64 + rdoff);
        fa1 = *(const bf16x8*)(bA + (wm + 16 + lr) * 64 + rdoff);
        fs0 = *(const bf16x8*)(bS + (wm +  0 + lr) * 64 + rdoff);
        fs1 = *(const bf16x8*)(bS + (wm + 16 + lr) * 64 + rdoff);
        if (st) STAGE_A(sb, kt + 3);
        __builtin_amdgcn_s_barrier();
        asm volatile("s_waitcnt lgkmcnt(0)" ::: "memory");
        __builtin_amdgcn_sched_barrier(0);
        __builtin_amdgcn_s_setprio(1);
        #pragma unroll
        for (int j = 0; j < 4; ++j) {
            accRe[0][j] = __builtin_amdgcn_mfma_f32_16x16x32_bf16(fa0, fb[j], accRe[0][j], 0, 0, 0);
            accIm[0][j] = __builtin_amdgcn_mfma_f32_16x16x32_bf16(fs0, fb[j], accIm[0][j], 0, 0, 0);
        }
        #pragma unroll
        for (int j = 0; j < 4; ++j) {
            accRe[1][j] = __builtin_amdgcn_mfma_f32_16x16x32_bf16(fa1, fb[j], accRe[1][j], 0, 0, 0);
            accIm[1][j] = __builtin_amdgcn_mfma_f32_16x16x32_bf16(fs1, fb[j], accIm[1][j], 0, 0, 0);
        }
        __builtin_amdgcn_s_setprio(0);
        __builtin_amdgcn_s_barrier();

        // ================= phase B =================
        bf16x8 fa2, fa3, fs2, fs3;
        fa2 = *(const bf16x8*)(bA + (wm + 32 + lr) * 64 + rdoff);
        fa3 = *(const bf16x8*)(bA + (wm + 48 + lr) * 64 + rdoff);
        fs2 = *(const bf16x8*)(bS + (wm + 32 + lr) * 64 + rdoff);
        fs3 = *(const bf16x8*)(bS + (wm + 48 + lr) * 64 + rdoff);
        if (st) STAGE_X(sb, kt + 3);
        __builtin_amdgcn_s_barrier();
        asm volatile("s_waitcnt lgkmcnt(0)" ::: "memory");
        __builtin_amdgcn_sched_barrier(0);
        __builtin_amdgcn_s_setprio(1);
        #pragma unroll
        for (int j = 0; j < 4; ++j) {
            accRe[2][j] = __builtin_amdgcn_mfma_f32_16x16x32_bf16(fa2, fb[j], accRe[2][j], 0, 0, 0);
            accIm[2][j] = __builtin_amdgcn_mfma_f32_16x16x32_bf16(fs2, fb[j], accIm[2][j], 0, 0, 0);
        }
        #pragma unroll
        for (int j = 0; j < 4; ++j) {
            accRe[3][j] = __builtin_amdgcn_mfma_f32_16x16x32_bf16(fa3, fb[j], accRe[3][j], 0, 0, 0);
            accIm[3][j] = __builtin_amdgcn_mfma_f32_16x16x32_bf16(fs3, fb[j], accIm[3][j], 0, 0, 0);
        }
        __builtin_amdgcn_s_setprio(0);
        // ---- tile boundary: counted vmcnt (oldest staged tile must be done)
        if (kt <= 28)      asm volatile("s_waitcnt vmcnt(8)" ::: "memory");
        else if (kt == 29) asm volatile("s_waitcnt vmcnt(4)" ::: "memory");
        else if (kt == 30) asm volatile("s_waitcnt vmcnt(0)" ::: "memory");
        __builtin_amdgcn_s_barrier();
    }
    #undef STAGE_A
    #undef STAGE_X

    // ---- epilogue: pdp[r][m..m+3] = (Re^2+Im^2)/2046^2 as bf16 (8B stores)
    // C/D layout (m89): col = lane&15 (r), row = (lane>>4)*4 + q (m)
    const float inv = 1.0f / ((float)FFT_N * (float)FFT_N);
    #pragma unroll
    for (int i = 0; i < 4; ++i)
        #pragma unroll
        for (int j = 0; j < 4; ++j) {
            int m = m0 + wm + i * 16 + (lane >> 4) * 4;
            int r = r0 + wr + j * 16 + (lane & 15);
            ushort4 o;
            #pragma unroll
            for (int q = 0; q < 4; ++q) {
                float re = accRe[i][j][q], im = accIm[i][j][q];
                ((u16*)&o)[q] = f2bf((re * re + im * im) * inv);
            }
            *(ushort4*)(pdp + (size_t)r * IN_N + m) = o;
        }
}

// ---------------------------------------------------------------------------
// Kernel 4: per-row-pair stats (symmetry: weight 2 for k=1..1022, 1 for 0,1023)
// delay = 1023*(1 - w0)  =>  |d_p - d_t|/2046 = 0.5*|w0_p - w0_t|
// ---------------------------------------------------------------------------
__device__ __forceinline__ float breduce(float v, float* red, int t, int op) {
    __syncthreads();
    red[t] = v;
    __syncthreads();
    for (int s = 128; s > 0; s >>= 1) {
        if (t < s) {
            float x = red[t], y = red[t + s];
            red[t] = (op == 0) ? (x + y) : (op == 1) ? fmaxf(x, y) : fminf(x, y);
        }
        __syncthreads();
    }
    return red[0];
}

__global__ __launch_bounds__(256) void row_stats_kernel(
    const u16* __restrict__ pdp,
    float* __restrict__ mse_rows, float* __restrict__ dd_rows) {

    __shared__ float red[256];
    const int r = blockIdx.x;
    const int t = threadIdx.x;
    const u16* pp = pdp + (size_t)r * IN_N;
    const u16* pt = pdp + (size_t)(NROWS + r) * IN_N;
    ushort4 up = *(const ushort4*)(pp + t * 4);
    ushort4 ut = *(const ushort4*)(pt + t * 4);
    float a[4] = {bf2f(up.x), bf2f(up.y), bf2f(up.z), bf2f(up.w)};
    float b[4] = {bf2f(ut.x), bf2f(ut.y), bf2f(ut.z), bf2f(ut.w)};

    float wsp = 0.f, wst = 0.f;
    float mxp = -1e30f, mnp = 1e30f, mxt = -1e30f, mnt = 1e30f;
    #pragma unroll
    for (int i = 0; i < 4; ++i) {
        int k = t * 4 + i;
        float wgt = (k == 0 || k == 1023) ? 1.f : 2.f;
        wsp += wgt * a[i];        wst += wgt * b[i];
        mxp = fmaxf(mxp, a[i]);   mnp = fminf(mnp, a[i]);
        mxt = fmaxf(mxt, b[i]);   mnt = fminf(mnt, b[i]);
    }
    float Ep  = breduce(wsp, red, t, 0);
    float Et  = breduce(wst, red, t, 0);
    float Mp  = breduce(mxp, red, t, 1);
    float mp_ = breduce(mnp, red, t, 2);
    float Mt  = breduce(mxt, red, t, 1);
    float mt_ = breduce(mnt, red, t, 2);

    float scp = (Ep < 1e-8f) ? 1.f : 1.f / Ep;
    float sct = (Et < 1e-8f) ? 1.f : 1.f / Et;
    float rngp = fmaxf(scp * (Mp - mp_), 1e-8f);
    float rngt = fmaxf(sct * (Mt - mt_), 1e-8f);
    float cfp = 10.f * scp / rngp;        // score_k = cfp * raw_pdp_k
    float cft = 10.f * sct / rngt;
    float smp = cfp * Mp;                 // max score
    float smt = cft * Mt;

    float zp = 0.f, zt = 0.f, ms = 0.f;
    #pragma unroll
    for (int i = 0; i < 4; ++i) {
        int k = t * 4 + i;
        float wgt = (k == 0 || k == 1023) ? 1.f : 2.f;
        zp += wgt * expf(cfp * a[i] - smp);
        zt += wgt * expf(cft * b[i] - smt);
        float d = a[i] * scp - b[i] * sct;
        ms += wgt * d * d;
    }
    float Zp  = breduce(zp, red, t, 0);
    float Zt  = breduce(zt, red, t, 0);
    float MSE = breduce(ms, red, t, 0);

    if (t == 0) {
        float w0p = expf(cfp * a[0] - smp) / Zp;   // k=0 lives in thread 0
        float w0t = expf(cft * b[0] - smt) / Zt;
        mse_rows[r] = MSE;
        dd_rows[r]  = 0.5f * fabsf(w0p - w0t);
    }
}

// ---------------------------------------------------------------------------
// Kernel 5: final scalar reduce.
// ---------------------------------------------------------------------------
__global__ __launch_bounds__(256) void final_kernel(
    const float* __restrict__ mse_rows, const float* __restrict__ dd_rows,
    float* __restrict__ out) {
    __shared__ float r1[256];
    __shared__ float r2[256];
    int t = threadIdx.x;
    float s1 = 0.f, s2 = 0.f;
    for (int r = t; r < NROWS; r += 256) { s1 += mse_rows[r]; s2 += dd_rows[r]; }
    r1[t] = s1; r2[t] = s2;
    __syncthreads();
    for (int s = 128; s > 0; s >>= 1) {
        if (t < s) { r1[t] += r1[t + s]; r2[t] += r2[t + s]; }
        __syncthreads();
    }
    if (t == 0) {
        float mse = r1[0] / ((float)NROWS * (float)FFT_N);
        float dl  = r2[0] / (float)NROWS;
        out[0] = 0.7f * mse + 0.3f * dl;
    }
}

// ---------------------------------------------------------------------------
extern "C" void kernel_launch(void* const* d_in, const int* in_sizes, int n_in,
                              void* d_out, int out_size, void* d_ws, size_t ws_size,
                              hipStream_t stream) {
    const float* pred = (const float*)d_in[0];
    const float* tgt  = (const float*)d_in[1];
    float* out = (float*)d_out;

    char* ws = (char*)d_ws;
    u16* Xh   = (u16*)ws;                                   // 32 MiB
    u16* Wch  = (u16*)(ws + (size_t)32 * 1024 * 1024);      //  2 MiB
    u16* Wsh  = (u16*)(ws + (size_t)34 * 1024 * 1024);      //  2 MiB
    u16* pdp  = (u16*)(ws + (size_t)40 * 1024 * 1024);      // 32 MiB
    float* mse_rows = (float*)(ws + (size_t)72 * 1024 * 1024);
    float* dd_rows  = mse_rows + NROWS;

    twiddle_kernel<<<1024, 256, 0, stream>>>(Wch, Wsh);
    convert_kernel<<<NTOT * IN_N / 4 / 256, 256, 0, stream>>>(pred, tgt, Xh);

    dft_pdp_mfma<<<512, 512, 0, stream>>>(Wch, Wsh, Xh, pdp);

    row_stats_kernel<<<NROWS, 256, 0, stream>>>(pdp, mse_rows, dd_rows);
    final_kernel<<<1, 256, 0, stream>>>(mse_rows, dd_rows, out);
}

// Round 6
// 136.997 us; speedup vs baseline: 6.6354x; 1.0122x over previous
//
#include <hip/hip_runtime.h>
#include <math.h>

#define IN_N   1024
#define NROWS  8192      // rows per tensor
#define NTOT   16384     // both tensors
#define FFT_N  2046

typedef unsigned short u16;
typedef __attribute__((ext_vector_type(8))) __bf16 bf16x8;
typedef __attribute__((ext_vector_type(4))) float  f32x4;

// ---- bf16 helpers (RTNE) --------------------------------------------------
__device__ __forceinline__ u16 f2bf(float f) {
    unsigned u = __builtin_bit_cast(unsigned, f);
    unsigned r = (u + 0x7fffu + ((u >> 16) & 1u)) >> 16;
    return (u16)r;
}
__device__ __forceinline__ float bf2f(u16 h) {
    unsigned u = ((unsigned)h) << 16;
    return __builtin_bit_cast(float, u);
}

// ---- async global->LDS, 16B per lane (dest = wave-uniform base + lane*16) --
__device__ __forceinline__ void gload_lds16(const void* g, void* l) {
    __builtin_amdgcn_global_load_lds(
        (__attribute__((address_space(1))) void*)g,
        (__attribute__((address_space(3))) void*)l, 16, 0, 0);
}

// ---------------------------------------------------------------------------
// Kernel 1: twiddle tables (bf16 hi only — X's own bf16 rounding dominates).
// ---------------------------------------------------------------------------
__global__ void twiddle_kernel(u16* __restrict__ Wc, u16* __restrict__ Ws) {
    int k = blockIdx.x;
    int n0 = threadIdx.x * 4;
    const float c = 6.28318530717958647692f / 2046.0f;
    ushort4 oc, os;
    #pragma unroll
    for (int i = 0; i < 4; ++i) {
        int n = n0 + i;
        int m = (k * n) % FFT_N;
        float a = (float)m * c;
        float sv, cv;
        sincosf(a, &sv, &cv);
        ((u16*)&oc)[i] = f2bf(cv);
        ((u16*)&os)[i] = f2bf(sv);
    }
    size_t o = (size_t)k * IN_N + n0;
    *(ushort4*)(Wc + o) = oc;
    *(ushort4*)(Ws + o) = os;
}

// ---------------------------------------------------------------------------
// Kernel 2: convert X (pred ++ tgt) fp32 -> bf16 (RTNE).
// ---------------------------------------------------------------------------
__global__ __launch_bounds__(256) void convert_kernel(
    const float* __restrict__ pred, const float* __restrict__ tgt,
    u16* __restrict__ Xh) {
    size_t gid = (size_t)blockIdx.x * 256 + threadIdx.x;   // float4 index
    size_t e = gid * 4;
    const size_t half = (size_t)NROWS * IN_N;
    const float* s = (e < half) ? (pred + e) : (tgt + (e - half));
    float4 v = *(const float4*)s;
    ushort4 o;
    o.x = f2bf(v.x); o.y = f2bf(v.y); o.z = f2bf(v.z); o.w = f2bf(v.w);
    *(ushort4*)(Xh + e) = o;
}

// ---------------------------------------------------------------------------
// Kernel 3: MFMA DFT + |.|^2, counted vmcnt AND counted lgkmcnt pipeline.
// ds_reads for phase P issued during phase P-1; the wait before each MFMA
// cluster is lgkmcnt(4) = only the just-issued next-phase batch outstanding.
// 2 barriers per K-tile: B1 (buf kt+1 staged) and B2 (tile-kt reads drained).
// Bank swizzle from R5 (slot ^= (row>>1)&3) kept: conflicts measured 0.
// ---------------------------------------------------------------------------
#define BM 128
#define BN 256
#define BK 32
#define NKT 32     // K tiles = 1024/32

#define FENCE() asm volatile("" ::: "memory")

__global__ __launch_bounds__(512, 2) void dft_pdp_mfma(
    const u16* __restrict__ Wc, const u16* __restrict__ Ws,
    const u16* __restrict__ Xh, u16* __restrict__ pdp) {

    // per buffer: A(cos) 8KB | S(sin) 8KB | X 16KB  = 32KB; x4 buffers
    __shared__ __align__(16) char lds[4][32768];

    // ---- XCD-aware decode (512 blocks, 8 XCDs, bijective)
    const int bid  = blockIdx.x;
    const int xcd  = bid & 7;
    const int slot = bid >> 3;                  // 0..63
    const int m0 = (slot & 7) * BM;
    const int r0 = (xcd * 8 + (slot >> 3)) * BN;

    const int t    = threadIdx.x;
    const int w    = t >> 6;                    // 0..7
    const int lane = t & 63;
    const int wm = (w & 1) * 64;                // wave m offset
    const int wr = (w >> 1) * 64;               // wave r offset
    const int lr = lane & 15;                   // frag row within 16
    // read-side swizzled k-chunk byte offset: slot = g ^ ((row>>1)&3)
    const int rdoff = (((lane >> 4) ^ ((lane >> 1) & 3)) << 4);

    // staging source pre-swizzle (rule 21): thread t -> LDS row t>>2, slot t&3
    const int srow  = t >> 2;                   // 0..127
    const int sslot = (t & 3) ^ ((t >> 3) & 3);
    const size_t aOfs  = (size_t)(m0 + srow) * 2048 + sslot * 16;
    const size_t xOfs0 = (size_t)(r0 + srow) * 2048 + sslot * 16;
    const size_t xOfs1 = (size_t)(r0 + 128 + srow) * 2048 + sslot * 16;
    const int woff = w << 10;                   // wave-uniform LDS base part

    f32x4 accRe[4][4], accIm[4][4];
    #pragma unroll
    for (int i = 0; i < 4; ++i)
        #pragma unroll
        for (int j = 0; j < 4; ++j)
            #pragma unroll
            for (int q = 0; q < 4; ++q) { accRe[i][j][q] = 0.f; accIm[i][j][q] = 0.f; }

    #define STAGE_A(buf, kt) do { \
        gload_lds16((const char*)Wc + aOfs + (size_t)(kt) * 64, &lds[buf][0] + woff); \
        gload_lds16((const char*)Ws + aOfs + (size_t)(kt) * 64, &lds[buf][0] + 8192 + woff); \
    } while (0)
    #define STAGE_X(buf, kt) do { \
        gload_lds16((const char*)Xh + xOfs0 + (size_t)(kt) * 64, &lds[buf][0] + 16384 + woff); \
        gload_lds16((const char*)Xh + xOfs1 + (size_t)(kt) * 64, &lds[buf][0] + 24576 + woff); \
    } while (0)
    // fragment loads (byte offsets in one 32KB buffer)
    #define LDA(buf, off) (*(const bf16x8*)(&lds[buf][0] + (wm + (off) + lr) * 64 + rdoff))
    #define LDSN(buf, off) (*(const bf16x8*)(&lds[buf][0] + 8192 + (wm + (off) + lr) * 64 + rdoff))
    #define LDX(buf, j)   (*(const bf16x8*)(&lds[buf][0] + 16384 + (wr + (j) * 16 + lr) * 64 + rdoff))

    // ---- prologue: stage tiles 0,1,2; ensure tile 0; preload R_A(0)
    STAGE_A(0, 0); STAGE_X(0, 0);
    STAGE_A(1, 1); STAGE_X(1, 1);
    STAGE_A(2, 2); STAGE_X(2, 2);
    asm volatile("s_waitcnt vmcnt(8)" ::: "memory");
    __builtin_amdgcn_s_barrier();
    FENCE();

    bf16x8 fb0, fb1, fb2, fb3, fa0, fa1, fa2, fa3, fs0, fs1, fs2, fs3;
    fb0 = LDX(0, 0); fb1 = LDX(0, 1); fb2 = LDX(0, 2); fb3 = LDX(0, 3);
    fa0 = LDA(0, 0); fa1 = LDA(0, 16); fs0 = LDSN(0, 0); fs1 = LDSN(0, 16);

    for (int kt = 0; kt < NKT; ++kt) {
        const int bcur  = kt & 3;
        const int bnext = (kt + 1) & 3;
        const int sb    = (kt + 3) & 3;
        const bool st   = (kt + 3) < NKT;       // kt <= 28
        const bool more = (kt + 1) < NKT;

        // ================= phase A =================
        fa2 = LDA(bcur, 32); fa3 = LDA(bcur, 48);       // R_B(kt): 4 reads
        fs2 = LDSN(bcur, 32); fs3 = LDSN(bcur, 48);
        if (st) STAGE_A(sb, kt + 3);
        asm volatile("s_waitcnt lgkmcnt(4)" ::: "memory");   // R_A(kt) ready
        __builtin_amdgcn_sched_barrier(0);
        __builtin_amdgcn_s_setprio(1);
        accRe[0][0] = __builtin_amdgcn_mfma_f32_16x16x32_bf16(fa0, fb0, accRe[0][0], 0, 0, 0);
        accIm[0][0] = __builtin_amdgcn_mfma_f32_16x16x32_bf16(fs0, fb0, accIm[0][0], 0, 0, 0);
        accRe[0][1] = __builtin_amdgcn_mfma_f32_16x16x32_bf16(fa0, fb1, accRe[0][1], 0, 0, 0);
        accIm[0][1] = __builtin_amdgcn_mfma_f32_16x16x32_bf16(fs0, fb1, accIm[0][1], 0, 0, 0);
        accRe[0][2] = __builtin_amdgcn_mfma_f32_16x16x32_bf16(fa0, fb2, accRe[0][2], 0, 0, 0);
        accIm[0][2] = __builtin_amdgcn_mfma_f32_16x16x32_bf16(fs0, fb2, accIm[0][2], 0, 0, 0);
        accRe[0][3] = __builtin_amdgcn_mfma_f32_16x16x32_bf16(fa0, fb3, accRe[0][3], 0, 0, 0);
        accIm[0][3] = __builtin_amdgcn_mfma_f32_16x16x32_bf16(fs0, fb3, accIm[0][3], 0, 0, 0);
        accRe[1][0] = __builtin_amdgcn_mfma_f32_16x16x32_bf16(fa1, fb0, accRe[1][0], 0, 0, 0);
        accIm[1][0] = __builtin_amdgcn_mfma_f32_16x16x32_bf16(fs1, fb0, accIm[1][0], 0, 0, 0);
        accRe[1][1] = __builtin_amdgcn_mfma_f32_16x16x32_bf16(fa1, fb1, accRe[1][1], 0, 0, 0);
        accIm[1][1] = __builtin_amdgcn_mfma_f32_16x16x32_bf16(fs1, fb1, accIm[1][1], 0, 0, 0);
        accRe[1][2] = __builtin_amdgcn_mfma_f32_16x16x32_bf16(fa1, fb2, accRe[1][2], 0, 0, 0);
        accIm[1][2] = __builtin_amdgcn_mfma_f32_16x16x32_bf16(fs1, fb2, accIm[1][2], 0, 0, 0);
        accRe[1][3] = __builtin_amdgcn_mfma_f32_16x16x32_bf16(fa1, fb3, accRe[1][3], 0, 0, 0);
        accIm[1][3] = __builtin_amdgcn_mfma_f32_16x16x32_bf16(fs1, fb3, accIm[1][3], 0, 0, 0);
        __builtin_amdgcn_s_setprio(0);

        // ================= phase B =================
        // ensure staging for tile kt+1 complete (counted vmcnt, never 0 early)
        if (kt <= NKT - 4)      asm volatile("s_waitcnt vmcnt(6)" ::: "memory");
        else if (kt == NKT - 3) asm volatile("s_waitcnt vmcnt(4)" ::: "memory");
        else                    asm volatile("s_waitcnt vmcnt(0)" ::: "memory");
        __builtin_amdgcn_s_barrier();            // B1: buf kt+1 staged (all waves)
        FENCE();
        if (more) {                              // fa01/fs01(kt+1): 4 reads
            fa0 = LDA(bnext, 0); fa1 = LDA(bnext, 16);
            fs0 = LDSN(bnext, 0); fs1 = LDSN(bnext, 16);
        }
        if (st) STAGE_X(sb, kt + 3);
        if (more) asm volatile("s_waitcnt lgkmcnt(4)" ::: "memory");  // R_B(kt) ready
        else      asm volatile("s_waitcnt lgkmcnt(0)" ::: "memory");
        __builtin_amdgcn_sched_barrier(0);
        __builtin_amdgcn_s_setprio(1);
        accRe[2][0] = __builtin_amdgcn_mfma_f32_16x16x32_bf16(fa2, fb0, accRe[2][0], 0, 0, 0);
        accIm[2][0] = __builtin_amdgcn_mfma_f32_16x16x32_bf16(fs2, fb0, accIm[2][0], 0, 0, 0);
        accRe[2][1] = __builtin_amdgcn_mfma_f32_16x16x32_bf16(fa2, fb1, accRe[2][1], 0, 0, 0);
        accIm[2][1] = __builtin_amdgcn_mfma_f32_16x16x32_bf16(fs2, fb1, accIm[2][1], 0, 0, 0);
        accRe[2][2] = __builtin_amdgcn_mfma_f32_16x16x32_bf16(fa2, fb2, accRe[2][2], 0, 0, 0);
        accIm[2][2] = __builtin_amdgcn_mfma_f32_16x16x32_bf16(fs2, fb2, accIm[2][2], 0, 0, 0);
        accRe[2][3] = __builtin_amdgcn_mfma_f32_16x16x32_bf16(fa2, fb3, accRe[2][3], 0, 0, 0);
        accIm[2][3] = __builtin_amdgcn_mfma_f32_16x16x32_bf16(fs2, fb3, accIm[2][3], 0, 0, 0);
        accRe[3][0] = __builtin_amdgcn_mfma_f32_16x16x32_bf16(fa3, fb0, accRe[3][0], 0, 0, 0);
        accIm[3][0] = __builtin_amdgcn_mfma_f32_16x16x32_bf16(fs3, fb0, accIm[3][0], 0, 0, 0);
        accRe[3][1] = __builtin_amdgcn_mfma_f32_16x16x32_bf16(fa3, fb1, accRe[3][1], 0, 0, 0);
        accIm[3][1] = __builtin_amdgcn_mfma_f32_16x16x32_bf16(fs3, fb1, accIm[3][1], 0, 0, 0);
        accRe[3][2] = __builtin_amdgcn_mfma_f32_16x16x32_bf16(fa3, fb2, accRe[3][2], 0, 0, 0);
        accIm[3][2] = __builtin_amdgcn_mfma_f32_16x16x32_bf16(fs3, fb2, accIm[3][2], 0, 0, 0);
        accRe[3][3] = __builtin_amdgcn_mfma_f32_16x16x32_bf16(fa3, fb3, accRe[3][3], 0, 0, 0);
        accIm[3][3] = __builtin_amdgcn_mfma_f32_16x16x32_bf16(fs3, fb3, accIm[3][3], 0, 0, 0);
        __builtin_amdgcn_s_setprio(0);
        if (more) {                              // fb(kt+1): AFTER MFMA_B (WAR)
            fb0 = LDX(bnext, 0); fb1 = LDX(bnext, 1);
            fb2 = LDX(bnext, 2); fb3 = LDX(bnext, 3);
        }
        __builtin_amdgcn_s_barrier();            // B2: tile-kt reads drained
        FENCE();
    }
    #undef STAGE_A
    #undef STAGE_X
    #undef LDA
    #undef LDSN
    #undef LDX

    // ---- epilogue: pdp[r][m..m+3] = (Re^2+Im^2)/2046^2 as bf16 (8B stores)
    // C/D layout (m89): col = lane&15 (r), row = (lane>>4)*4 + q (m)
    const float inv = 1.0f / ((float)FFT_N * (float)FFT_N);
    #pragma unroll
    for (int i = 0; i < 4; ++i)
        #pragma unroll
        for (int j = 0; j < 4; ++j) {
            int m = m0 + wm + i * 16 + (lane >> 4) * 4;
            int r = r0 + wr + j * 16 + (lane & 15);
            ushort4 o;
            #pragma unroll
            for (int q = 0; q < 4; ++q) {
                float re = accRe[i][j][q], im = accIm[i][j][q];
                ((u16*)&o)[q] = f2bf((re * re + im * im) * inv);
            }
            *(ushort4*)(pdp + (size_t)r * IN_N + m) = o;
        }
}

// ---------------------------------------------------------------------------
// Kernel 4: per-row-pair stats (symmetry: weight 2 for k=1..1022, 1 for 0,1023)
// delay = 1023*(1 - w0)  =>  |d_p - d_t|/2046 = 0.5*|w0_p - w0_t|
// ---------------------------------------------------------------------------
__device__ __forceinline__ float breduce(float v, float* red, int t, int op) {
    __syncthreads();
    red[t] = v;
    __syncthreads();
    for (int s = 128; s > 0; s >>= 1) {
        if (t < s) {
            float x = red[t], y = red[t + s];
            red[t] = (op == 0) ? (x + y) : (op == 1) ? fmaxf(x, y) : fminf(x, y);
        }
        __syncthreads();
    }
    return red[0];
}

__global__ __launch_bounds__(256) void row_stats_kernel(
    const u16* __restrict__ pdp,
    float* __restrict__ mse_rows, float* __restrict__ dd_rows) {

    __shared__ float red[256];
    const int r = blockIdx.x;
    const int t = threadIdx.x;
    const u16* pp = pdp + (size_t)r * IN_N;
    const u16* pt = pdp + (size_t)(NROWS + r) * IN_N;
    ushort4 up = *(const ushort4*)(pp + t * 4);
    ushort4 ut = *(const ushort4*)(pt + t * 4);
    float a[4] = {bf2f(up.x), bf2f(up.y), bf2f(up.z), bf2f(up.w)};
    float b[4] = {bf2f(ut.x), bf2f(ut.y), bf2f(ut.z), bf2f(ut.w)};

    float wsp = 0.f, wst = 0.f;
    float mxp = -1e30f, mnp = 1e30f, mxt = -1e30f, mnt = 1e30f;
    #pragma unroll
    for (int i = 0; i < 4; ++i) {
        int k = t * 4 + i;
        float wgt = (k == 0 || k == 1023) ? 1.f : 2.f;
        wsp += wgt * a[i];        wst += wgt * b[i];
        mxp = fmaxf(mxp, a[i]);   mnp = fminf(mnp, a[i]);
        mxt = fmaxf(mxt, b[i]);   mnt = fminf(mnt, b[i]);
    }
    float Ep  = breduce(wsp, red, t, 0);
    float Et  = breduce(wst, red, t, 0);
    float Mp  = breduce(mxp, red, t, 1);
    float mp_ = breduce(mnp, red, t, 2);
    float Mt  = breduce(mxt, red, t, 1);
    float mt_ = breduce(mnt, red, t, 2);

    float scp = (Ep < 1e-8f) ? 1.f : 1.f / Ep;
    float sct = (Et < 1e-8f) ? 1.f : 1.f / Et;
    float rngp = fmaxf(scp * (Mp - mp_), 1e-8f);
    float rngt = fmaxf(sct * (Mt - mt_), 1e-8f);
    float cfp = 10.f * scp / rngp;        // score_k = cfp * raw_pdp_k
    float cft = 10.f * sct / rngt;
    float smp = cfp * Mp;                 // max score
    float smt = cft * Mt;

    float zp = 0.f, zt = 0.f, ms = 0.f;
    #pragma unroll
    for (int i = 0; i < 4; ++i) {
        int k = t * 4 + i;
        float wgt = (k == 0 || k == 1023) ? 1.f : 2.f;
        zp += wgt * expf(cfp * a[i] - smp);
        zt += wgt * expf(cft * b[i] - smt);
        float d = a[i] * scp - b[i] * sct;
        ms += wgt * d * d;
    }
    float Zp  = breduce(zp, red, t, 0);
    float Zt  = breduce(zt, red, t, 0);
    float MSE = breduce(ms, red, t, 0);

    if (t == 0) {
        float w0p = expf(cfp * a[0] - smp) / Zp;   // k=0 lives in thread 0
        float w0t = expf(cft * b[0] - smt) / Zt;
        mse_rows[r] = MSE;
        dd_rows[r]  = 0.5f * fabsf(w0p - w0t);
    }
}

// ---------------------------------------------------------------------------
// Kernel 5: final scalar reduce.
// ---------------------------------------------------------------------------
__global__ __launch_bounds__(256) void final_kernel(
    const float* __restrict__ mse_rows, const float* __restrict__ dd_rows,
    float* __restrict__ out) {
    __shared__ float r1[256];
    __shared__ float r2[256];
    int t = threadIdx.x;
    float s1 = 0.f, s2 = 0.f;
    for (int r = t; r < NROWS; r += 256) { s1 += mse_rows[r]; s2 += dd_rows[r]; }
    r1[t] = s1; r2[t] = s2;
    __syncthreads();
    for (int s = 128; s > 0; s >>= 1) {
        if (t < s) { r1[t] += r1[t + s]; r2[t] += r2[t + s]; }
        __syncthreads();
    }
    if (t == 0) {
        float mse = r1[0] / ((float)NROWS * (float)FFT_N);
        float dl  = r2[0] / (float)NROWS;
        out[0] = 0.7f * mse + 0.3f * dl;
    }
}

// ---------------------------------------------------------------------------
extern "C" void kernel_launch(void* const* d_in, const int* in_sizes, int n_in,
                              void* d_out, int out_size, void* d_ws, size_t ws_size,
                              hipStream_t stream) {
    const float* pred = (const float*)d_in[0];
    const float* tgt  = (const float*)d_in[1];
    float* out = (float*)d_out;

    char* ws = (char*)d_ws;
    u16* Xh   = (u16*)ws;                                   // 32 MiB
    u16* Wch  = (u16*)(ws + (size_t)32 * 1024 * 1024);      //  2 MiB
    u16* Wsh  = (u16*)(ws + (size_t)34 * 1024 * 1024);      //  2 MiB
    u16* pdp  = (u16*)(ws + (size_t)40 * 1024 * 1024);      // 32 MiB
    float* mse_rows = (float*)(ws + (size_t)72 * 1024 * 1024);
    float* dd_rows  = mse_rows + NROWS;

    twiddle_kernel<<<1024, 256, 0, stream>>>(Wch, Wsh);
    convert_kernel<<<NTOT * IN_N / 4 / 256, 256, 0, stream>>>(pred, tgt, Xh);

    dft_pdp_mfma<<<512, 512, 0, stream>>>(Wch, Wsh, Xh, pdp);

    row_stats_kernel<<<NROWS, 256, 0, stream>>>(pdp, mse_rows, dd_rows);
    final_kernel<<<1, 256, 0, stream>>>(mse_rows, dd_rows, out);
}